// Round 1
// baseline (949.160 us; speedup 1.0000x reference)
//
#include <hip/hip_runtime.h>
#include <hip/hip_bf16.h>
#include <math.h>

#define N_NODES  20000
#define E_EDGES  320000
#define E_TOT    (E_EDGES + N_NODES)
#define F_INF    256
#define HEADS    8
#define CDIM     64
#define HID      512
#define B_GRAPHS 64
#define NCLS     10

// ---------------------------------------------------------------- utils
__global__ __launch_bounds__(256) void zero_ints(int* p, int n) {
    int i = blockIdx.x * 256 + threadIdx.x;
    if (i < n) p[i] = 0;
}

// ---------------------------------------------------------------- GEMM (fp32, A[MxK] @ B[Kx512] -> C[Mx512])
__global__ __launch_bounds__(256) void gemm_f32(const float* __restrict__ A,
                                                const float* __restrict__ B,
                                                float* __restrict__ C,
                                                int M, int K) {
    __shared__ float As[16][68];
    __shared__ float Bs[16][68];
    const int tid = threadIdx.x;
    const int tx = tid & 15, ty = tid >> 4;
    const int row0 = blockIdx.x * 64, col0 = blockIdx.y * 64;

    const int arow = tid >> 2;          // 0..63
    const int akc  = (tid & 3) * 4;     // 0,4,8,12
    const int brow = tid >> 4;          // 0..15
    const int bcol = (tid & 15) * 4;    // 0..60

    float c[4][4] = {};

    for (int kk = 0; kk < K; kk += 16) {
        float4 a4;
        if (row0 + arow < M)
            a4 = *(const float4*)(A + (size_t)(row0 + arow) * K + kk + akc);
        else
            a4 = make_float4(0.f, 0.f, 0.f, 0.f);
        As[akc + 0][arow] = a4.x;
        As[akc + 1][arow] = a4.y;
        As[akc + 2][arow] = a4.z;
        As[akc + 3][arow] = a4.w;
        *(float4*)&Bs[brow][bcol] =
            *(const float4*)(B + (size_t)(kk + brow) * HID + col0 + bcol);
        __syncthreads();
#pragma unroll
        for (int k = 0; k < 16; ++k) {
            float a[4], b[4];
#pragma unroll
            for (int i = 0; i < 4; ++i) a[i] = As[k][ty * 4 + i];
#pragma unroll
            for (int j = 0; j < 4; ++j) b[j] = Bs[k][tx * 4 + j];
#pragma unroll
            for (int i = 0; i < 4; ++i)
#pragma unroll
                for (int j = 0; j < 4; ++j)
                    c[i][j] += a[i] * b[j];
        }
        __syncthreads();
    }
#pragma unroll
    for (int i = 0; i < 4; ++i) {
        int r = row0 + ty * 4 + i;
        if (r < M) {
#pragma unroll
            for (int j = 0; j < 4; ++j)
                C[(size_t)r * HID + col0 + tx * 4 + j] = c[i][j];
        }
    }
}

// ---------------------------------------------------------------- al_s / al_d  (one wave per (n,h))
__global__ __launch_bounds__(256) void compute_al(const float* __restrict__ xt,
                                                  const float* __restrict__ a_src,
                                                  const float* __restrict__ a_dst,
                                                  float* __restrict__ al_s,
                                                  float* __restrict__ al_d) {
    int tid = threadIdx.x;
    int w = blockIdx.x * 4 + (tid >> 6);     // global wave id
    int lane = tid & 63;
    int n = w >> 3;
    int h = w & 7;
    float v = xt[(size_t)n * HID + h * CDIM + lane];
    float s = v * a_src[h * CDIM + lane];
    float d = v * a_dst[h * CDIM + lane];
#pragma unroll
    for (int off = 32; off; off >>= 1) {
        s += __shfl_xor(s, off);
        d += __shfl_xor(d, off);
    }
    if (lane == 0) {
        al_s[n * HEADS + h] = s;
        al_d[n * HEADS + h] = d;
    }
}

// ---------------------------------------------------------------- CSR build
__global__ __launch_bounds__(256) void count_edges(const int* __restrict__ ei,
                                                   int* __restrict__ counts) {
    int e = blockIdx.x * 256 + threadIdx.x;
    if (e < E_TOT) {
        int dst = (e < E_EDGES) ? ei[E_EDGES + e] : (e - E_EDGES);
        atomicAdd(&counts[dst], 1);
    }
}

__global__ __launch_bounds__(1024) void scan_counts(const int* __restrict__ counts,
                                                    int* __restrict__ offsets,
                                                    int* __restrict__ cursor) {
    __shared__ int sdata[1024];
    __shared__ int carry_s;
    int tid = threadIdx.x;
    if (tid == 0) { carry_s = 0; offsets[0] = 0; }
    __syncthreads();
    for (int base = 0; base < N_NODES; base += 1024) {
        int i = base + tid;
        int v = (i < N_NODES) ? counts[i] : 0;
        sdata[tid] = v;
        __syncthreads();
        for (int off = 1; off < 1024; off <<= 1) {
            int t = (tid >= off) ? sdata[tid - off] : 0;
            __syncthreads();
            sdata[tid] += t;
            __syncthreads();
        }
        int incl = sdata[tid] + carry_s;
        if (i < N_NODES) {
            offsets[i + 1] = incl;
            cursor[i] = incl - v;   // exclusive offset
        }
        __syncthreads();
        if (tid == 0) carry_s += sdata[1023];
        __syncthreads();
    }
}

__global__ __launch_bounds__(256) void scatter_edges(const int* __restrict__ ei,
                                                     int* __restrict__ cursor,
                                                     int* __restrict__ csr) {
    int e = blockIdx.x * 256 + threadIdx.x;
    if (e < E_TOT) {
        int dst = (e < E_EDGES) ? ei[E_EDGES + e] : (e - E_EDGES);
        int pos = atomicAdd(&cursor[dst], 1);
        csr[pos] = e;
    }
}

// ---------------------------------------------------------------- GAT aggregation (one block per dst node)
__global__ __launch_bounds__(256) void gat_aggregate(const float* __restrict__ xt,
                                                     const float* __restrict__ al_s,
                                                     const float* __restrict__ al_d,
                                                     const int* __restrict__ offsets,
                                                     const int* __restrict__ csr,
                                                     const int* __restrict__ ei,
                                                     const float* __restrict__ bias,
                                                     float* __restrict__ out) {
    const int n = blockIdx.x;
    const int tid = threadIdx.x;
    const int beg = offsets[n], end = offsets[n + 1];
    const int deg = end - beg;

    __shared__ float ald_sh[HEADS];
    __shared__ float m_sh[HEADS], s_sh[HEADS];
    __shared__ float alpha_sh[32][HEADS];
    __shared__ int   src_sh[32];

    if (tid < HEADS) ald_sh[tid] = al_d[n * HEADS + tid];
    __syncthreads();

    const int g = tid >> 5;        // head for phases 1/2
    const int lane32 = tid & 31;

    // phase 1: per-head max of leaky_relu(al_s[src,h]+al_d[n,h])
    float m = -1e30f;
    for (int i = lane32; i < deg; i += 32) {
        int e = csr[beg + i];
        int srcn = (e < E_EDGES) ? ei[e] : (e - E_EDGES);
        float ev = al_s[srcn * HEADS + g] + ald_sh[g];
        ev = (ev >= 0.f) ? ev : 0.2f * ev;
        m = fmaxf(m, ev);
    }
#pragma unroll
    for (int off = 16; off; off >>= 1) m = fmaxf(m, __shfl_xor(m, off));
    if (lane32 == 0) m_sh[g] = m;
    __syncthreads();

    // phase 2: per-head sum of exp
    float mh = m_sh[g];
    float s = 0.f;
    for (int i = lane32; i < deg; i += 32) {
        int e = csr[beg + i];
        int srcn = (e < E_EDGES) ? ei[e] : (e - E_EDGES);
        float ev = al_s[srcn * HEADS + g] + ald_sh[g];
        ev = (ev >= 0.f) ? ev : 0.2f * ev;
        s += expf(ev - mh);
    }
#pragma unroll
    for (int off = 16; off; off >>= 1) s += __shfl_xor(s, off);
    if (lane32 == 0) s_sh[g] = s;
    __syncthreads();

    // phase 3: accumulate 512 channels (thread -> channels tid and tid+256)
    float acc0 = 0.f, acc1 = 0.f;
    const int j0 = tid, j1 = tid + 256;
    const int h0 = j0 >> 6, h1 = j1 >> 6;

    for (int cbase = 0; cbase < deg; cbase += 32) {
        int cnum = min(32, deg - cbase);
        __syncthreads();
        {
            int el = tid >> 3, hh = tid & 7;
            if (el < cnum) {
                int e = csr[beg + cbase + el];
                int srcn = (e < E_EDGES) ? ei[e] : (e - E_EDGES);
                if (hh == 0) src_sh[el] = srcn;
                float ev = al_s[srcn * HEADS + hh] + ald_sh[hh];
                ev = (ev >= 0.f) ? ev : 0.2f * ev;
                alpha_sh[el][hh] = expf(ev - m_sh[hh]) / (s_sh[hh] + 1e-16f);
            }
        }
        __syncthreads();
        for (int el = 0; el < cnum; ++el) {
            const float* row = xt + (size_t)src_sh[el] * HID;
            acc0 += alpha_sh[el][h0] * row[j0];
            acc1 += alpha_sh[el][h1] * row[j1];
        }
    }

    float v0 = acc0 + bias[j0];
    float v1 = acc1 + bias[j1];
    v0 = (v0 > 0.f) ? v0 : expm1f(v0);   // ELU
    v1 = (v1 > 0.f) ? v1 : expm1f(v1);
    out[(size_t)n * HID + j0] = v0;
    out[(size_t)n * HID + j1] = v1;
}

// ---------------------------------------------------------------- pooling
__global__ __launch_bounds__(128) void find_bounds(const int* __restrict__ batch,
                                                   int* __restrict__ bounds) {
    int b = threadIdx.x;
    if (b <= B_GRAPHS) {
        int lo = 0, hi = N_NODES;
        while (lo < hi) {
            int mid = (lo + hi) >> 1;
            if (batch[mid] < b) lo = mid + 1; else hi = mid;
        }
        bounds[b] = lo;
    }
}

__global__ __launch_bounds__(256) void pool_kernel(const float* __restrict__ h,
                                                   const int* __restrict__ bounds,
                                                   float* __restrict__ outG) {
    int b = blockIdx.x;
    int tid = threadIdx.x;
    int s = bounds[b], e = bounds[b + 1];
    float a0 = 0.f, a1 = 0.f;
    for (int n = s; n < e; ++n) {
        a0 += h[(size_t)n * HID + tid];
        a1 += h[(size_t)n * HID + tid + 256];
    }
    float cnt = fmaxf((float)(e - s), 1.0f);
    outG[b * HID + tid] = a0 / cnt;
    outG[b * HID + tid + 256] = a1 / cnt;
}

// ---------------------------------------------------------------- classifier + softmax
__global__ __launch_bounds__(64) void classifier_kernel(const float* __restrict__ hG,
                                                        const float* __restrict__ Wl,
                                                        const float* __restrict__ bl,
                                                        float* __restrict__ outP) {
    int b = blockIdx.x;
    int tid = threadIdx.x;
    __shared__ float row[HID];
    __shared__ float logit[NCLS];
    for (int j = tid; j < HID; j += 64) row[j] = hG[b * HID + j];
    __syncthreads();
    if (tid < NCLS) {
        float acc = bl[tid];
        for (int j = 0; j < HID; ++j) acc += row[j] * Wl[j * NCLS + tid];
        logit[tid] = acc;
    }
    __syncthreads();
    if (tid == 0) {
        float mx = logit[0];
        for (int k = 1; k < NCLS; ++k) mx = fmaxf(mx, logit[k]);
        float ssum = 0.f, ex[NCLS];
        for (int k = 0; k < NCLS; ++k) { ex[k] = expf(logit[k] - mx); ssum += ex[k]; }
        for (int k = 0; k < NCLS; ++k) outP[b * NCLS + k] = ex[k] / ssum;
    }
}

// ---------------------------------------------------------------- launch
extern "C" void kernel_launch(void* const* d_in, const int* in_sizes, int n_in,
                              void* d_out, int out_size, void* d_ws, size_t ws_size,
                              hipStream_t stream) {
    const float* x     = (const float*)d_in[0];
    const int*   ei    = (const int*)d_in[1];
    const int*   batch = (const int*)d_in[2];
    const float* W[3]  = { (const float*)d_in[3], (const float*)d_in[7],  (const float*)d_in[11] };
    const float* as_[3] = { (const float*)d_in[4], (const float*)d_in[8],  (const float*)d_in[12] };
    const float* ad_[3] = { (const float*)d_in[5], (const float*)d_in[9],  (const float*)d_in[13] };
    const float* bb[3] = { (const float*)d_in[6], (const float*)d_in[10], (const float*)d_in[14] };
    const float* Wl    = (const float*)d_in[15];
    const float* bl    = (const float*)d_in[16];

    // workspace layout
    char* ws = (char*)d_ws;
    float* xt   = (float*)ws;                        ws += (size_t)N_NODES * HID * 4;
    float* hbuf = (float*)ws;                        ws += (size_t)N_NODES * HID * 4;
    float* als  = (float*)ws;                        ws += (size_t)N_NODES * HEADS * 4;
    float* ald  = (float*)ws;                        ws += (size_t)N_NODES * HEADS * 4;
    int* counts  = (int*)ws;                         ws += (size_t)N_NODES * 4;
    int* offsets = (int*)ws;                         ws += (size_t)(N_NODES + 1) * 4;
    int* cursor  = (int*)ws;                         ws += (size_t)N_NODES * 4;
    int* csr     = (int*)ws;                         ws += (size_t)E_TOT * 4;
    int* bounds  = (int*)ws;                         ws += (size_t)(B_GRAPHS + 1) * 4;

    float* hG = (float*)d_out;                 // 64*512
    float* probs = (float*)d_out + (size_t)B_GRAPHS * HID;

    // ---- CSR build (identical every call; rebuilt for determinism/no-caching)
    zero_ints<<<(N_NODES + 255) / 256, 256, 0, stream>>>(counts, N_NODES);
    count_edges<<<(E_TOT + 255) / 256, 256, 0, stream>>>(ei, counts);
    scan_counts<<<1, 1024, 0, stream>>>(counts, offsets, cursor);
    scatter_edges<<<(E_TOT + 255) / 256, 256, 0, stream>>>(ei, cursor, csr);
    find_bounds<<<1, 128, 0, stream>>>(batch, bounds);

    dim3 ggrid((N_NODES + 63) / 64, HID / 64);

    // ---- layer 1
    gemm_f32<<<ggrid, 256, 0, stream>>>(x, W[0], xt, N_NODES, F_INF);
    compute_al<<<N_NODES * HEADS / 4, 256, 0, stream>>>(xt, as_[0], ad_[0], als, ald);
    gat_aggregate<<<N_NODES, 256, 0, stream>>>(xt, als, ald, offsets, csr, ei, bb[0], hbuf);

    // ---- layer 2
    gemm_f32<<<ggrid, 256, 0, stream>>>(hbuf, W[1], xt, N_NODES, HID);
    compute_al<<<N_NODES * HEADS / 4, 256, 0, stream>>>(xt, as_[1], ad_[1], als, ald);
    gat_aggregate<<<N_NODES, 256, 0, stream>>>(xt, als, ald, offsets, csr, ei, bb[1], hbuf);

    // ---- layer 3
    gemm_f32<<<ggrid, 256, 0, stream>>>(hbuf, W[2], xt, N_NODES, HID);
    compute_al<<<N_NODES * HEADS / 4, 256, 0, stream>>>(xt, as_[2], ad_[2], als, ald);
    gat_aggregate<<<N_NODES, 256, 0, stream>>>(xt, als, ald, offsets, csr, ei, bb[2], hbuf);

    // ---- pool + classify
    pool_kernel<<<B_GRAPHS, 256, 0, stream>>>(hbuf, bounds, hG);
    classifier_kernel<<<B_GRAPHS, 64, 0, stream>>>(hG, Wl, bl, probs);
}

// Round 2
// 738.713 us; speedup vs baseline: 1.2849x; 1.2849x over previous
//
#include <hip/hip_runtime.h>
#include <hip/hip_bf16.h>
#include <math.h>

#define N_NODES  20000
#define E_EDGES  320000
#define E_TOT    (E_EDGES + N_NODES)
#define F_INF    256
#define HEADS    8
#define CDIM     64
#define HID      512
#define B_GRAPHS 64
#define NCLS     10
#define M_PAD    20096          // 157 * 128

typedef __attribute__((ext_vector_type(8))) short short8;
typedef __attribute__((ext_vector_type(4))) float f32x4;

__device__ inline unsigned short f2bf(float x) {
    unsigned u = __builtin_bit_cast(unsigned, x);
    u += 0x7fff + ((u >> 16) & 1);          // round-to-nearest-even
    return (unsigned short)(u >> 16);
}
__device__ inline float bf2f(unsigned short h) {
    unsigned u = ((unsigned)h) << 16;
    return __builtin_bit_cast(float, u);
}

#define GLOAD_LDS16(g, l) __builtin_amdgcn_global_load_lds(                     \
        (const __attribute__((address_space(1))) void*)(g),                     \
        (__attribute__((address_space(3))) void*)(l), 16, 0, 0)

// ---------------------------------------------------------------- utils
__global__ __launch_bounds__(256) void zero_ints(int* p, int n) {
    int i = blockIdx.x * 256 + threadIdx.x;
    if (i < n) p[i] = 0;
}

// ---------------------------------------------------------------- fp32 -> bf16 hi/lo split (row-padded)
__global__ __launch_bounds__(256) void split_pad(const float* __restrict__ src,
                                                 unsigned short* __restrict__ hi,
                                                 unsigned short* __restrict__ lo,
                                                 int M, int K, long total) {
    long i = ((long)blockIdx.x * 256 + threadIdx.x) * 4;
    if (i >= total) return;
    int row = (int)(i / K);
    float4 v = make_float4(0.f, 0.f, 0.f, 0.f);
    if (row < M) v = *(const float4*)(src + i);
    ushort4 h, l;
    h.x = f2bf(v.x); l.x = f2bf(v.x - bf2f(h.x));
    h.y = f2bf(v.y); l.y = f2bf(v.y - bf2f(h.y));
    h.z = f2bf(v.z); l.z = f2bf(v.z - bf2f(h.z));
    h.w = f2bf(v.w); l.w = f2bf(v.w - bf2f(h.w));
    *(ushort4*)(hi + i) = h;
    *(ushort4*)(lo + i) = l;
}

// ---------------------------------------------------------------- B[K][512] -> Bt_hi/lo[512][K]
__global__ __launch_bounds__(256) void transpose_split_B(const float* __restrict__ B,
                                                         unsigned short* __restrict__ Bthi,
                                                         unsigned short* __restrict__ Btlo,
                                                         int K) {
    __shared__ float t[32][33];
    int n0 = blockIdx.x * 32, k0 = blockIdx.y * 32;
    int tx = threadIdx.x & 31, ty = threadIdx.x >> 5;     // 32 x 8
    for (int i = ty; i < 32; i += 8) t[i][tx] = B[(size_t)(k0 + i) * HID + n0 + tx];
    __syncthreads();
    for (int i = ty; i < 32; i += 8) {
        float v = t[tx][i];                                // = B[k0+tx][n0+i]
        unsigned short h = f2bf(v);
        unsigned short l = f2bf(v - bf2f(h));
        Bthi[(size_t)(n0 + i) * K + k0 + tx] = h;
        Btlo[(size_t)(n0 + i) * K + k0 + tx] = l;
    }
}

// ---------------------------------------------------------------- bf16x3 MFMA GEMM: C[M x 512] = A[M x K] @ B[K x 512]
// A given as hi/lo bf16, row-major, padded to M_PAD rows (zeros).
// B given as hi/lo bf16 TRANSPOSED: Bt[n][k].
__global__ __launch_bounds__(256) void gemm_mfma(const unsigned short* __restrict__ Ahi,
                                                 const unsigned short* __restrict__ Alo,
                                                 const unsigned short* __restrict__ Bhi,
                                                 const unsigned short* __restrict__ Blo,
                                                 float* __restrict__ C,
                                                 int M, int K) {
    __shared__ short AsHi[4096], AsLo[4096], BsHi[4096], BsLo[4096]; // 4 x 8KB, [128 rows][32 k] swizzled
    const int tid = threadIdx.x;
    const int w = tid >> 6, lane = tid & 63;
    const int wr = w >> 1, wc = w & 1;
    const int row0 = blockIdx.x * 128, col0 = blockIdx.y * 128;

    // staging: LDS 16B-unit u holds tile (row=u>>2, kgrp=(u&3)^(row&3)).
    // wave w stages units [w*128, w*128+128) of each tile (2 instrs of 64 units).
    long offA[2], offB[2];
    int ldsU[2];
#pragma unroll
    for (int i = 0; i < 2; ++i) {
        int u = w * 128 + i * 64 + lane;
        int row = u >> 2;
        int kg = (u & 3) ^ (row & 3);
        offA[i] = ((long)(row0 + row) * K + kg * 8) * 2;   // bytes
        offB[i] = ((long)(col0 + row) * K + kg * 8) * 2;
        ldsU[i] = (w * 128 + i * 64) * 8;                  // short index of LDS base
    }

    // ds_read byte offsets (swizzled): frag needs (row, k=(lane>>4)*8 ..+8)
    const int r16 = lane & 15, kg = lane >> 4;
    int aOff[4], bOff[4];
#pragma unroll
    for (int i = 0; i < 4; ++i) {
        int row = wr * 64 + i * 16 + r16;
        aOff[i] = (row * 4 + (kg ^ (row & 3))) * 16;
        int col = wc * 64 + i * 16 + r16;
        bOff[i] = (col * 4 + (kg ^ (col & 3))) * 16;
    }

    const char* pAhi = (const char*)Ahi;
    const char* pAlo = (const char*)Alo;
    const char* pBhi = (const char*)Bhi;
    const char* pBlo = (const char*)Blo;

    f32x4 acc[4][4] = {};

    for (int kk = 0; kk < K; kk += 32) {
        long kb = (long)kk * 2;
        __syncthreads();                         // previous step's ds_reads done
#pragma unroll
        for (int i = 0; i < 2; ++i) {
            GLOAD_LDS16(pAhi + offA[i] + kb, AsHi + ldsU[i]);
            GLOAD_LDS16(pAlo + offA[i] + kb, AsLo + ldsU[i]);
            GLOAD_LDS16(pBhi + offB[i] + kb, BsHi + ldsU[i]);
            GLOAD_LDS16(pBlo + offB[i] + kb, BsLo + ldsU[i]);
        }
        __syncthreads();                         // drains vmcnt before barrier

        short8 ah[4], al[4], bh[4], bl[4];
#pragma unroll
        for (int i = 0; i < 4; ++i) {
            ah[i] = *(const short8*)((const char*)AsHi + aOff[i]);
            al[i] = *(const short8*)((const char*)AsLo + aOff[i]);
            bh[i] = *(const short8*)((const char*)BsHi + bOff[i]);
            bl[i] = *(const short8*)((const char*)BsLo + bOff[i]);
        }
#pragma unroll
        for (int i = 0; i < 4; ++i)
#pragma unroll
            for (int j = 0; j < 4; ++j) {
                acc[i][j] = __builtin_amdgcn_mfma_f32_16x16x32_bf16(ah[i], bh[j], acc[i][j], 0, 0, 0);
                acc[i][j] = __builtin_amdgcn_mfma_f32_16x16x32_bf16(ah[i], bl[j], acc[i][j], 0, 0, 0);
                acc[i][j] = __builtin_amdgcn_mfma_f32_16x16x32_bf16(al[i], bh[j], acc[i][j], 0, 0, 0);
            }
    }

    // epilogue: C/D layout col=lane&15, row=(lane>>4)*4+r
#pragma unroll
    for (int i = 0; i < 4; ++i) {
        int rbase = row0 + wr * 64 + i * 16 + (lane >> 4) * 4;
#pragma unroll
        for (int j = 0; j < 4; ++j) {
            int col = col0 + wc * 64 + j * 16 + r16;
#pragma unroll
            for (int r = 0; r < 4; ++r)
                if (rbase + r < M) C[(size_t)(rbase + r) * HID + col] = acc[i][j][r];
        }
    }
}

// ---------------------------------------------------------------- al_s / al_d  (one wave per (n,h))
__global__ __launch_bounds__(256) void compute_al(const float* __restrict__ xt,
                                                  const float* __restrict__ a_src,
                                                  const float* __restrict__ a_dst,
                                                  float* __restrict__ al_s,
                                                  float* __restrict__ al_d) {
    int tid = threadIdx.x;
    int w = blockIdx.x * 4 + (tid >> 6);     // global wave id
    int lane = tid & 63;
    int n = w >> 3;
    int h = w & 7;
    float v = xt[(size_t)n * HID + h * CDIM + lane];
    float s = v * a_src[h * CDIM + lane];
    float d = v * a_dst[h * CDIM + lane];
#pragma unroll
    for (int off = 32; off; off >>= 1) {
        s += __shfl_xor(s, off);
        d += __shfl_xor(d, off);
    }
    if (lane == 0) {
        al_s[n * HEADS + h] = s;
        al_d[n * HEADS + h] = d;
    }
}

// ---------------------------------------------------------------- CSR build
__global__ __launch_bounds__(256) void count_edges(const int* __restrict__ ei,
                                                   int* __restrict__ counts) {
    int e = blockIdx.x * 256 + threadIdx.x;
    if (e < E_TOT) {
        int dst = (e < E_EDGES) ? ei[E_EDGES + e] : (e - E_EDGES);
        atomicAdd(&counts[dst], 1);
    }
}

__global__ __launch_bounds__(1024) void scan_counts(const int* __restrict__ counts,
                                                    int* __restrict__ offsets,
                                                    int* __restrict__ cursor) {
    __shared__ int sdata[1024];
    __shared__ int carry_s;
    int tid = threadIdx.x;
    if (tid == 0) { carry_s = 0; offsets[0] = 0; }
    __syncthreads();
    for (int base = 0; base < N_NODES; base += 1024) {
        int i = base + tid;
        int v = (i < N_NODES) ? counts[i] : 0;
        sdata[tid] = v;
        __syncthreads();
        for (int off = 1; off < 1024; off <<= 1) {
            int t = (tid >= off) ? sdata[tid - off] : 0;
            __syncthreads();
            sdata[tid] += t;
            __syncthreads();
        }
        int incl = sdata[tid] + carry_s;
        if (i < N_NODES) {
            offsets[i + 1] = incl;
            cursor[i] = incl - v;   // exclusive offset
        }
        __syncthreads();
        if (tid == 0) carry_s += sdata[1023];
        __syncthreads();
    }
}

__global__ __launch_bounds__(256) void scatter_edges(const int* __restrict__ ei,
                                                     int* __restrict__ cursor,
                                                     int* __restrict__ csr) {
    int e = blockIdx.x * 256 + threadIdx.x;
    if (e < E_TOT) {
        int dst = (e < E_EDGES) ? ei[E_EDGES + e] : (e - E_EDGES);
        int pos = atomicAdd(&cursor[dst], 1);
        csr[pos] = e;
    }
}

// ---------------------------------------------------------------- GAT aggregation (one block per dst node)
__global__ __launch_bounds__(256) void gat_aggregate(const float* __restrict__ xt,
                                                     const float* __restrict__ al_s,
                                                     const float* __restrict__ al_d,
                                                     const int* __restrict__ offsets,
                                                     const int* __restrict__ csr,
                                                     const int* __restrict__ ei,
                                                     const float* __restrict__ bias,
                                                     float* __restrict__ out) {
    const int n = blockIdx.x;
    const int tid = threadIdx.x;
    const int beg = offsets[n], end = offsets[n + 1];
    const int deg = end - beg;

    __shared__ float ald_sh[HEADS];
    __shared__ float m_sh[HEADS], s_sh[HEADS];
    __shared__ float alpha_sh[32][HEADS];
    __shared__ int   src_sh[32];

    if (tid < HEADS) ald_sh[tid] = al_d[n * HEADS + tid];
    __syncthreads();

    const int g = tid >> 5;        // head for phases 1/2
    const int lane32 = tid & 31;

    // phase 1: per-head max of leaky_relu(al_s[src,h]+al_d[n,h])
    float m = -1e30f;
    for (int i = lane32; i < deg; i += 32) {
        int e = csr[beg + i];
        int srcn = (e < E_EDGES) ? ei[e] : (e - E_EDGES);
        float ev = al_s[srcn * HEADS + g] + ald_sh[g];
        ev = (ev >= 0.f) ? ev : 0.2f * ev;
        m = fmaxf(m, ev);
    }
#pragma unroll
    for (int off = 16; off; off >>= 1) m = fmaxf(m, __shfl_xor(m, off));
    if (lane32 == 0) m_sh[g] = m;
    __syncthreads();

    // phase 2: per-head sum of exp
    float mh = m_sh[g];
    float s = 0.f;
    for (int i = lane32; i < deg; i += 32) {
        int e = csr[beg + i];
        int srcn = (e < E_EDGES) ? ei[e] : (e - E_EDGES);
        float ev = al_s[srcn * HEADS + g] + ald_sh[g];
        ev = (ev >= 0.f) ? ev : 0.2f * ev;
        s += expf(ev - mh);
    }
#pragma unroll
    for (int off = 16; off; off >>= 1) s += __shfl_xor(s, off);
    if (lane32 == 0) s_sh[g] = s;
    __syncthreads();

    // phase 3: accumulate 512 channels (thread -> channels tid and tid+256)
    float acc0 = 0.f, acc1 = 0.f;
    const int j0 = tid, j1 = tid + 256;
    const int h0 = j0 >> 6, h1 = j1 >> 6;

    for (int cbase = 0; cbase < deg; cbase += 32) {
        int cnum = min(32, deg - cbase);
        __syncthreads();
        {
            int el = tid >> 3, hh = tid & 7;
            if (el < cnum) {
                int e = csr[beg + cbase + el];
                int srcn = (e < E_EDGES) ? ei[e] : (e - E_EDGES);
                if (hh == 0) src_sh[el] = srcn;
                float ev = al_s[srcn * HEADS + hh] + ald_sh[hh];
                ev = (ev >= 0.f) ? ev : 0.2f * ev;
                alpha_sh[el][hh] = expf(ev - m_sh[hh]) / (s_sh[hh] + 1e-16f);
            }
        }
        __syncthreads();
        for (int el = 0; el < cnum; ++el) {
            const float* row = xt + (size_t)src_sh[el] * HID;
            acc0 += alpha_sh[el][h0] * row[j0];
            acc1 += alpha_sh[el][h1] * row[j1];
        }
    }

    float v0 = acc0 + bias[j0];
    float v1 = acc1 + bias[j1];
    v0 = (v0 > 0.f) ? v0 : expm1f(v0);   // ELU
    v1 = (v1 > 0.f) ? v1 : expm1f(v1);
    out[(size_t)n * HID + j0] = v0;
    out[(size_t)n * HID + j1] = v1;
}

// ---------------------------------------------------------------- pooling
__global__ __launch_bounds__(128) void find_bounds(const int* __restrict__ batch,
                                                   int* __restrict__ bounds) {
    int b = threadIdx.x;
    if (b <= B_GRAPHS) {
        int lo = 0, hi = N_NODES;
        while (lo < hi) {
            int mid = (lo + hi) >> 1;
            if (batch[mid] < b) lo = mid + 1; else hi = mid;
        }
        bounds[b] = lo;
    }
}

__global__ __launch_bounds__(256) void pool_kernel(const float* __restrict__ h,
                                                   const int* __restrict__ bounds,
                                                   float* __restrict__ outG) {
    int b = blockIdx.x;
    int tid = threadIdx.x;
    int s = bounds[b], e = bounds[b + 1];
    float a0 = 0.f, a1 = 0.f;
    for (int n = s; n < e; ++n) {
        a0 += h[(size_t)n * HID + tid];
        a1 += h[(size_t)n * HID + tid + 256];
    }
    float cnt = fmaxf((float)(e - s), 1.0f);
    outG[b * HID + tid] = a0 / cnt;
    outG[b * HID + tid + 256] = a1 / cnt;
}

// ---------------------------------------------------------------- classifier + softmax
__global__ __launch_bounds__(64) void classifier_kernel(const float* __restrict__ hG,
                                                        const float* __restrict__ Wl,
                                                        const float* __restrict__ bl,
                                                        float* __restrict__ outP) {
    int b = blockIdx.x;
    int tid = threadIdx.x;
    __shared__ float row[HID];
    __shared__ float logit[NCLS];
    for (int j = tid; j < HID; j += 64) row[j] = hG[b * HID + j];
    __syncthreads();
    if (tid < NCLS) {
        float acc = bl[tid];
        for (int j = 0; j < HID; ++j) acc += row[j] * Wl[j * NCLS + tid];
        logit[tid] = acc;
    }
    __syncthreads();
    if (tid == 0) {
        float mx = logit[0];
        for (int k = 1; k < NCLS; ++k) mx = fmaxf(mx, logit[k]);
        float ssum = 0.f, ex[NCLS];
        for (int k = 0; k < NCLS; ++k) { ex[k] = expf(logit[k] - mx); ssum += ex[k]; }
        for (int k = 0; k < NCLS; ++k) outP[b * NCLS + k] = ex[k] / ssum;
    }
}

// ---------------------------------------------------------------- launch
extern "C" void kernel_launch(void* const* d_in, const int* in_sizes, int n_in,
                              void* d_out, int out_size, void* d_ws, size_t ws_size,
                              hipStream_t stream) {
    const float* x     = (const float*)d_in[0];
    const int*   ei    = (const int*)d_in[1];
    const int*   batch = (const int*)d_in[2];
    const float* W[3]  = { (const float*)d_in[3], (const float*)d_in[7],  (const float*)d_in[11] };
    const float* as_[3] = { (const float*)d_in[4], (const float*)d_in[8],  (const float*)d_in[12] };
    const float* ad_[3] = { (const float*)d_in[5], (const float*)d_in[9],  (const float*)d_in[13] };
    const float* bb[3] = { (const float*)d_in[6], (const float*)d_in[10], (const float*)d_in[14] };
    const float* Wl    = (const float*)d_in[15];
    const float* bl    = (const float*)d_in[16];

    // workspace layout (16B-aligned chunks first)
    char* ws = (char*)d_ws;
    unsigned short* Ahi = (unsigned short*)ws;       ws += (size_t)M_PAD * HID * 2;   // 20.6 MB
    unsigned short* Alo = (unsigned short*)ws;       ws += (size_t)M_PAD * HID * 2;
    unsigned short* Bthi = (unsigned short*)ws;      ws += (size_t)HID * HID * 2;     // 0.5 MB
    unsigned short* Btlo = (unsigned short*)ws;      ws += (size_t)HID * HID * 2;
    float* xt   = (float*)ws;                        ws += (size_t)N_NODES * HID * 4;
    float* hbuf = (float*)ws;                        ws += (size_t)N_NODES * HID * 4;
    float* als  = (float*)ws;                        ws += (size_t)N_NODES * HEADS * 4;
    float* ald  = (float*)ws;                        ws += (size_t)N_NODES * HEADS * 4;
    int* counts  = (int*)ws;                         ws += (size_t)N_NODES * 4;
    int* offsets = (int*)ws;                         ws += (size_t)(N_NODES + 1) * 4;
    int* cursor  = (int*)ws;                         ws += (size_t)N_NODES * 4;
    int* csr     = (int*)ws;                         ws += (size_t)E_TOT * 4;
    int* bounds  = (int*)ws;                         ws += (size_t)(B_GRAPHS + 1) * 4;

    float* hG = (float*)d_out;                 // 64*512
    float* probs = (float*)d_out + (size_t)B_GRAPHS * HID;

    // ---- CSR build (identical every call; rebuilt for determinism/no-caching)
    zero_ints<<<(N_NODES + 255) / 256, 256, 0, stream>>>(counts, N_NODES);
    count_edges<<<(E_TOT + 255) / 256, 256, 0, stream>>>(ei, counts);
    scan_counts<<<1, 1024, 0, stream>>>(counts, offsets, cursor);
    scatter_edges<<<(E_TOT + 255) / 256, 256, 0, stream>>>(ei, cursor, csr);
    find_bounds<<<1, 128, 0, stream>>>(batch, bounds);

    dim3 ggrid(M_PAD / 128, HID / 128);   // (157, 4)

    // ---- layer 1 (K = 256)
    {
        long totA = (long)M_PAD * F_INF;
        split_pad<<<(int)(totA / 4 / 256), 256, 0, stream>>>(x, Ahi, Alo, N_NODES, F_INF, totA);
        transpose_split_B<<<dim3(HID / 32, F_INF / 32), 256, 0, stream>>>(W[0], Bthi, Btlo, F_INF);
        gemm_mfma<<<ggrid, 256, 0, stream>>>(Ahi, Alo, Bthi, Btlo, xt, N_NODES, F_INF);
        compute_al<<<N_NODES * HEADS / 4, 256, 0, stream>>>(xt, as_[0], ad_[0], als, ald);
        gat_aggregate<<<N_NODES, 256, 0, stream>>>(xt, als, ald, offsets, csr, ei, bb[0], hbuf);
    }

    // ---- layers 2,3 (K = 512)
    for (int L = 1; L < 3; ++L) {
        long totA = (long)M_PAD * HID;
        split_pad<<<(int)(totA / 4 / 256), 256, 0, stream>>>(hbuf, Ahi, Alo, N_NODES, HID, totA);
        transpose_split_B<<<dim3(HID / 32, HID / 32), 256, 0, stream>>>(W[L], Bthi, Btlo, HID);
        gemm_mfma<<<ggrid, 256, 0, stream>>>(Ahi, Alo, Bthi, Btlo, xt, N_NODES, HID);
        compute_al<<<N_NODES * HEADS / 4, 256, 0, stream>>>(xt, as_[L], ad_[L], als, ald);
        gat_aggregate<<<N_NODES, 256, 0, stream>>>(xt, als, ald, offsets, csr, ei, bb[L], hbuf);
    }

    // ---- pool + classify
    pool_kernel<<<B_GRAPHS, 256, 0, stream>>>(hbuf, bounds, hG);
    classifier_kernel<<<B_GRAPHS, 64, 0, stream>>>(hG, Wl, bl, probs);
}